// Round 17
// baseline (203.267 us; speedup 1.0000x reference)
//
#include <hip/hip_runtime.h>

#define D 128
#define HDIM 256
#define NB 8            // batch size (fixed by setup_inputs)
#define NSH 16          // wave-shards per row in topk kernel
#define CPS 16          // candidates per shard
#define RESC 32         // candidates rescored per row
#define PHW 16          // phW row stride (floats): [0..7]=ph, [8]=W2
#define WPAD 136        // wL row stride in ushorts (272 B: 16B-aligned, 2-way banks = free)

typedef short bf16x8 __attribute__((ext_vector_type(8)));
typedef float f32x4 __attribute__((ext_vector_type(4)));

__device__ __forceinline__ unsigned short f2bf(float x) {
    unsigned u = __float_as_uint(x);
    unsigned r = u + 0x7FFF + ((u >> 16) & 1);   // RNE (finite data)
    return (unsigned short)(r >> 16);
}
__device__ __forceinline__ bf16x8 pack_bf8(float4 u, float4 v) {
    union { bf16x8 v8; unsigned short s[8]; } r;
    r.s[0] = f2bf(u.x); r.s[1] = f2bf(u.y); r.s[2] = f2bf(u.z); r.s[3] = f2bf(u.w);
    r.s[4] = f2bf(v.x); r.s[5] = f2bf(v.y); r.s[6] = f2bf(v.z); r.s[7] = f2bf(v.w);
    return r.v8;
}

// key = (ordered_float << 32) | (0xFFFFFFFF - idx): max == (max val, min idx)
__device__ __forceinline__ unsigned long long sk_encode(float v, int idx) {
    unsigned u = __float_as_uint(v);
    u = (u & 0x80000000u) ? ~u : (u | 0x80000000u);
    return ((unsigned long long)u << 32) | (unsigned)(0xFFFFFFFFu - (unsigned)idx);
}
__device__ __forceinline__ float sk_val(unsigned long long key) {
    const unsigned u = (unsigned)(key >> 32);
    return (u & 0x80000000u) ? __uint_as_float(u & 0x7FFFFFFFu) : __uint_as_float(~u);
}
__device__ __forceinline__ int sk_idx(unsigned long long key) {
    return (int)(0xFFFFFFFFu - (unsigned)(key & 0xFFFFFFFFu));
}
__device__ __forceinline__ unsigned long long wave_max64(unsigned long long m) {
#pragma unroll
    for (int s = 32; s > 0; s >>= 1) {
        const unsigned long long o = __shfl_xor(m, s, 64);
        if (o > m) m = o;
    }
    return m;
}

// ---------------------------------------------------------------------------
// K1: prep. blocks 0..7: ph row b -> phW[h][b] (+W2 -> phW[h][8] from b==0).
//     blocks 8..39: w1tt = bf16(W1t^T), 4 k-cols each. (R16-proven.)
// ---------------------------------------------------------------------------
__global__ __launch_bounds__(HDIM) void prep_kernel(
        const int* __restrict__ head, const int* __restrict__ relation,
        const float* __restrict__ ent_emb, const float* __restrict__ rel_emb,
        const float* __restrict__ W1, const float* __restrict__ b1,
        const float* __restrict__ W2, float* __restrict__ phW,
        unsigned short* __restrict__ w1tt) {
    const int w = blockIdx.x;
    const int tid = threadIdx.x;
    if (w < NB) {
        const int b = w;
        const long hidx = head[b];
        const long ridx = relation[b];
        const float* hrow = ent_emb + hidx * D;
        const float* rrow = rel_emb + ridx * D;
        float acc = b1[tid];
#pragma unroll 8
        for (int d = 0; d < D; ++d)
            acc += hrow[d] * W1[d * HDIM + tid];       // coalesced across tid
#pragma unroll 8
        for (int d = 0; d < D; ++d)
            acc += rrow[d] * W1[(D + d) * HDIM + tid];
        phW[tid * PHW + b] = acc;
        if (b == 0) phW[tid * PHW + 8] = W2[tid];
    } else {
        const int k0 = (w - NB) * 4;
        const float* w1t = W1 + 2 * D * HDIM;
        unsigned short pk[4];
#pragma unroll
        for (int j = 0; j < 4; ++j)
            pk[j] = f2bf(w1t[(k0 + j) * HDIM + tid]);  // coalesced across tid
        *(ushort4*)(w1tt + tid * D + k0) = make_ushort4(pk[0], pk[1], pk[2], pk[3]);
    }
}

// ---------------------------------------------------------------------------
// K2: MFMA score — R16-proven (LDS-staged, 512 thr / 8 waves, 1 tile/wave,
// (512,2) bounds = 128-VGPR cap, spill-free).
// mfma_f32_16x16x32_bf16: A[m=lane&15][k=(lane>>4)*8+j]; B[k][n=lane&15];
// C: col(n)=lane&15, row(m)=(lane>>4)*4+reg.
// ---------------------------------------------------------------------------
__global__ __launch_bounds__(512, 2) void score_kernel(
        const float* __restrict__ ent_emb, const unsigned short* __restrict__ w1tt,
        const float* __restrict__ phW, float* __restrict__ scores, int E) {
    __shared__ __align__(16) unsigned short wL[HDIM][WPAD];   // 69.6 KB
    __shared__ float phB[NB][HDIM];                           //  8 KB  [b][h]
    __shared__ float w2L[HDIM];                               //  1 KB

    const int tid = threadIdx.x;
    const int lane = tid & 63;
    const int wave = tid >> 6;          // 0..7
    const int lm = lane & 15;
    const int q = lane >> 4;
    const int base_e = blockIdx.x * 128 + wave * 16;

    const float* arow = ent_emb + (size_t)min(base_e + lm, E - 1) * D;
    bf16x8 aF[4];
#pragma unroll
    for (int kk = 0; kk < 4; ++kk) {
        const float4 u = *(const float4*)(arow + kk * 32 + q * 8);
        const float4 v = *(const float4*)(arow + kk * 32 + q * 8 + 4);
        aF[kk] = pack_bf8(u, v);
    }

#pragma unroll
    for (int i = 0; i < 8; ++i) {
        const int c = i * 512 + tid;           // chunk of 8 ushorts
        const int row = c >> 4;                // 16 chunks per 128-ushort row
        const int col = (c & 15) << 3;
        *(uint4*)(&wL[row][col]) = *(const uint4*)(w1tt + row * D + col);
    }
    if (tid < HDIM) {
        const float4 p0 = *(const float4*)(phW + tid * PHW);
        const float4 p1 = *(const float4*)(phW + tid * PHW + 4);
        phB[0][tid] = p0.x; phB[1][tid] = p0.y; phB[2][tid] = p0.z; phB[3][tid] = p0.w;
        phB[4][tid] = p1.x; phB[5][tid] = p1.y; phB[6][tid] = p1.z; phB[7][tid] = p1.w;
        w2L[tid] = phW[tid * PHW + 8];
    }
    __syncthreads();   // the ONLY barrier

    float sp[NB * 4];
#pragma unroll
    for (int i = 0; i < NB * 4; ++i) sp[i] = 0.f;

#pragma unroll
    for (int t = 0; t < 16; ++t) {
        const int h = t * 16 + lm;             // lane's B-row & C-col
        bf16x8 bF[4];
#pragma unroll
        for (int kk = 0; kk < 4; ++kk)
            bF[kk] = *(const bf16x8*)(&wL[h][kk * 32 + q * 8]);   // 2-way banks: free

        float phv[8];
#pragma unroll
        for (int b = 0; b < NB; ++b) phv[b] = phB[b][h];   // 16 banks + broadcast
        const float w2v = w2L[h];

        f32x4 acc = (f32x4){0.f, 0.f, 0.f, 0.f};
#pragma unroll
        for (int kk = 0; kk < 4; ++kk)
            acc = __builtin_amdgcn_mfma_f32_16x16x32_bf16(aF[kk], bF[kk], acc, 0, 0, 0);

#pragma unroll
        for (int b = 0; b < NB; ++b)
#pragma unroll
            for (int r = 0; r < 4; ++r)
                sp[b * 4 + r] += fmaxf(phv[b] + acc[r], 0.f) * w2v;
    }

#pragma unroll
    for (int m = 1; m <= 8; m <<= 1) {
#pragma unroll
        for (int i = 0; i < NB * 4; ++i)
            sp[i] += __shfl_xor(sp[i], m, 64);
    }
    if (lm == 0) {
#pragma unroll
        for (int r = 0; r < 4; ++r) {
            const int e = base_e + q * 4 + r;
            if (e < E) {
#pragma unroll
                for (int b = 0; b < NB; ++b)
                    scores[(size_t)b * E + e] = sp[b * 4 + r];
            }
        }
    }
}

// ---------------------------------------------------------------------------
// K3 (R17): row top-k, fused scan + exact rescore + final. 8 blocks (1/row),
// 1024 threads = 16 waves. Wave w scans contiguous shard w (per-thread K=16
// retains every shard-top-16: dropping one needs 16 in-thread better elems,
// all shard-top-16 -> contradiction). Block merges 256 -> approx-top-32,
// rescores 32 exactly in fp32, emits final top-k. Replaces two dispatches.
// ---------------------------------------------------------------------------
__global__ __launch_bounds__(1024) void topk_final_kernel(
        const float* __restrict__ scores, int E,
        const float* __restrict__ ent_emb, const float* __restrict__ W1,
        const float* __restrict__ phW, const float* __restrict__ b2,
        int k, float* __restrict__ out) {
    const int row = blockIdx.x;
    const int tid = threadIdx.x;
    const int lane = tid & 63;
    const int wave = tid >> 6;          // 0..15

    __shared__ unsigned long long candL[NSH * CPS];          // 2 KB (256 keys)
    __shared__ unsigned long long top32[RESC];
    __shared__ int eIdx[RESC];
    __shared__ __align__(16) float entL[RESC][D];            // 16 KB
    __shared__ float red[16][8];
    __shared__ float exCand[RESC];

    // ---- Phase A: wave-shard scan (approx scores) ----
    {
        const int shard = (E + NSH - 1) / NSH;
        const int start = wave * shard;
        const int end = min(E, start + shard);
        const float* srow = scores + (size_t)row * E;

        unsigned long long keys[CPS];
#pragma unroll
        for (int i = 0; i < CPS; ++i) keys[i] = 0ull;

        for (int e = start + lane; e < end; e += 64) {
            unsigned long long key = sk_encode(srow[e], e);
            if (key > keys[CPS - 1]) {
#pragma unroll
                for (int j = 0; j < CPS; ++j) {
                    const bool gt = key > keys[j];
                    const unsigned long long mx = gt ? key : keys[j];
                    key = gt ? keys[j] : key;
                    keys[j] = mx;
                }
            }
        }
        for (int r = 0; r < CPS; ++r) {
            const unsigned long long m = wave_max64(keys[0]);
            if (keys[0] == m) {
#pragma unroll
                for (int j = 0; j < CPS - 1; ++j) keys[j] = keys[j + 1];
                keys[CPS - 1] = 0ull;
            }
            if (lane == 0) candL[wave * CPS + r] = m;
        }
        __syncthreads();
    }

    // ---- Phase B: block merge 256 -> approx-top-32 (wave 0) ----
    if (wave == 0) {
        unsigned long long m4[4];
#pragma unroll
        for (int j = 0; j < 4; ++j) m4[j] = candL[j * 64 + lane];
#pragma unroll
        for (int i = 0; i < 4; ++i)
#pragma unroll
            for (int j = 0; j < 3; ++j)
                if (m4[j] < m4[j + 1]) {
                    const unsigned long long t = m4[j];
                    m4[j] = m4[j + 1];
                    m4[j + 1] = t;
                }
        for (int r = 0; r < RESC; ++r) {
            const unsigned long long m = wave_max64(m4[0]);
            if (m4[0] == m) {
#pragma unroll
                for (int j = 0; j < 3; ++j) m4[j] = m4[j + 1];
                m4[3] = 0ull;
            }
            if (lane == 0) top32[r] = m;
        }
    }
    __syncthreads();

    // ---- Phase C: exact fp32 rescore of the 32 candidates ----
    if (tid < RESC) eIdx[tid] = min(sk_idx(top32[tid]), E - 1);
    __syncthreads();
    if (tid < RESC * (D / 4)) {                  // 1024 float4 loads
        const int r = tid >> 5, c4 = (tid & 31) * 4;
        *(float4*)(&entL[r][c4]) =
            *(const float4*)(ent_emb + (size_t)eIdx[r] * D + c4);
    }
    __syncthreads();

    const int h = tid & 255;                     // owned hidden unit
    const int cg = tid >> 8;                     // candidate group 0..3 (8 cands)
    const float* w1t = W1 + 2 * D * HDIM;
    float acc[8];
#pragma unroll
    for (int c = 0; c < 8; ++c) acc[c] = 0.f;
    for (int d0 = 0; d0 < D; d0 += 4) {
        float w[4];
#pragma unroll
        for (int j = 0; j < 4; ++j) w[j] = w1t[(d0 + j) * HDIM + h];    // coalesced
#pragma unroll
        for (int c = 0; c < 8; ++c) {
            const float4 f = *(const float4*)(&entL[cg * 8 + c][d0]);    // broadcast
            acc[c] += f.x * w[0] + f.y * w[1] + f.z * w[2] + f.w * w[3];
        }
    }
    const float phv = phW[h * PHW + row];
    const float w2v = phW[h * PHW + 8];
    float sc[8];
#pragma unroll
    for (int c = 0; c < 8; ++c) sc[c] = fmaxf(acc[c] + phv, 0.f) * w2v;

#pragma unroll
    for (int m = 1; m <= 32; m <<= 1)
#pragma unroll
        for (int c = 0; c < 8; ++c) sc[c] += __shfl_xor(sc[c], m, 64);
    if (lane == 0)
#pragma unroll
        for (int c = 0; c < 8; ++c) red[wave][c] = sc[c];   // wave covers 64 h's
    __syncthreads();
    if (tid < RESC) {                            // cand tid: cg'=tid>>3, c=tid&7
        const int cgp = tid >> 3, c = tid & 7;
        exCand[tid] = red[cgp * 4 + 0][c] + red[cgp * 4 + 1][c]
                    + red[cgp * 4 + 2][c] + red[cgp * 4 + 3][c] + b2[0];
    }
    __syncthreads();

    // ---- Phase D: final top-k from 32 exact keys ----
    if (wave == 0) {
        unsigned long long key = (lane < RESC)
            ? sk_encode(exCand[lane], eIdx[lane]) : 0ull;
        for (int r = 0; r < k; ++r) {
            const unsigned long long m = wave_max64(key);
            if (key == m) key = 0ull;
            if (lane == 0) {
                out[row * k + r] = (float)sk_idx(m);          // indices
                out[NB * k + row * k + r] = sk_val(m);        // scores
            }
        }
    }
}

// ---------------------------------------------------------------------------
extern "C" void kernel_launch(void* const* d_in, const int* in_sizes, int n_in,
                              void* d_out, int out_size, void* d_ws, size_t ws_size,
                              hipStream_t stream) {
    const int*   head     = (const int*)d_in[0];
    const int*   relation = (const int*)d_in[1];
    const float* ent_emb  = (const float*)d_in[3];
    const float* rel_emb  = (const float*)d_in[4];
    const float* W1       = (const float*)d_in[5];
    const float* b1       = (const float*)d_in[6];
    const float* W2       = (const float*)d_in[7];
    const float* b2       = (const float*)d_in[8];

    const int B = in_sizes[0];          // 8
    const int E = in_sizes[3] / D;      // 50000
    int k = out_size / (2 * B);         // 10
    if (k > CPS) k = CPS;

    char* ws = (char*)d_ws;
    float*          phW       = (float*)ws;                         //  16 KB
    unsigned short* w1tt      = (unsigned short*)(ws + 16384);      //  64 KB
    float*          scores    = (float*)(ws + 81920);               // 1.6 MB
    float*          out       = (float*)d_out;

    prep_kernel<<<NB + 32, HDIM, 0, stream>>>(head, relation, ent_emb, rel_emb,
                                              W1, b1, W2, phW, w1tt);
    const int nblk = (E + 127) / 128;
    score_kernel<<<nblk, 512, 0, stream>>>(ent_emb, w1tt, phW, scores, E);
    topk_final_kernel<<<NB, 1024, 0, stream>>>(scores, E, ent_emb, W1, phW,
                                               b2, k, out);
}

// Round 18
// 153.662 us; speedup vs baseline: 1.3228x; 1.3228x over previous
//
#include <hip/hip_runtime.h>

#define D 128
#define HDIM 256
#define NB 8            // batch size (fixed by setup_inputs)
#define NSHARD 32       // topk shards per row (256 blocks = 1/CU)
#define CPS 16          // candidates per shard
#define NCAND (NSHARD * CPS)   // 512 candidates per row
#define PHW 16          // phW row stride (floats): [0..7]=ph, [8]=W2
#define WPAD 136        // wL row stride in ushorts (272 B: 16B-aligned, 2-way banks = free)

typedef short bf16x8 __attribute__((ext_vector_type(8)));
typedef float f32x4 __attribute__((ext_vector_type(4)));

__device__ __forceinline__ unsigned short f2bf(float x) {
    unsigned u = __float_as_uint(x);
    unsigned r = u + 0x7FFF + ((u >> 16) & 1);   // RNE (finite data)
    return (unsigned short)(r >> 16);
}
__device__ __forceinline__ bf16x8 pack_bf8(float4 u, float4 v) {
    union { bf16x8 v8; unsigned short s[8]; } r;
    r.s[0] = f2bf(u.x); r.s[1] = f2bf(u.y); r.s[2] = f2bf(u.z); r.s[3] = f2bf(u.w);
    r.s[4] = f2bf(v.x); r.s[5] = f2bf(v.y); r.s[6] = f2bf(v.z); r.s[7] = f2bf(v.w);
    return r.v8;
}

// key = (ordered_float << 32) | (0xFFFFFFFF - idx): max == (max val, min idx)
__device__ __forceinline__ unsigned long long sk_encode(float v, int idx) {
    unsigned u = __float_as_uint(v);
    u = (u & 0x80000000u) ? ~u : (u | 0x80000000u);
    return ((unsigned long long)u << 32) | (unsigned)(0xFFFFFFFFu - (unsigned)idx);
}
__device__ __forceinline__ float sk_val(unsigned long long key) {
    const unsigned u = (unsigned)(key >> 32);
    return (u & 0x80000000u) ? __uint_as_float(u & 0x7FFFFFFFu) : __uint_as_float(~u);
}
__device__ __forceinline__ int sk_idx(unsigned long long key) {
    return (int)(0xFFFFFFFFu - (unsigned)(key & 0xFFFFFFFFu));
}
__device__ __forceinline__ unsigned long long wave_max64(unsigned long long m) {
#pragma unroll
    for (int s = 32; s > 0; s >>= 1) {
        const unsigned long long o = __shfl_xor(m, s, 64);
        if (o > m) m = o;
    }
    return m;
}

// ---------------------------------------------------------------------------
// K1: prep. blocks 0..7: ph row b -> phW[h][b] (+W2 -> phW[h][8] from b==0).
//     blocks 8..39: w1tt = bf16(W1t^T), 4 k-cols each. (R16-proven.)
// ---------------------------------------------------------------------------
__global__ __launch_bounds__(HDIM) void prep_kernel(
        const int* __restrict__ head, const int* __restrict__ relation,
        const float* __restrict__ ent_emb, const float* __restrict__ rel_emb,
        const float* __restrict__ W1, const float* __restrict__ b1,
        const float* __restrict__ W2, float* __restrict__ phW,
        unsigned short* __restrict__ w1tt) {
    const int w = blockIdx.x;
    const int tid = threadIdx.x;
    if (w < NB) {
        const int b = w;
        const long hidx = head[b];
        const long ridx = relation[b];
        const float* hrow = ent_emb + hidx * D;
        const float* rrow = rel_emb + ridx * D;
        float acc = b1[tid];
#pragma unroll 8
        for (int d = 0; d < D; ++d)
            acc += hrow[d] * W1[d * HDIM + tid];       // coalesced across tid
#pragma unroll 8
        for (int d = 0; d < D; ++d)
            acc += rrow[d] * W1[(D + d) * HDIM + tid];
        phW[tid * PHW + b] = acc;
        if (b == 0) phW[tid * PHW + 8] = W2[tid];
    } else {
        const int k0 = (w - NB) * 4;
        const float* w1t = W1 + 2 * D * HDIM;
        unsigned short pk[4];
#pragma unroll
        for (int j = 0; j < 4; ++j)
            pk[j] = f2bf(w1t[(k0 + j) * HDIM + tid]);  // coalesced across tid
        *(ushort4*)(w1tt + tid * D + k0) = make_ushort4(pk[0], pk[1], pk[2], pk[3]);
    }
}

// ---------------------------------------------------------------------------
// K2: MFMA score — R16-proven (LDS-staged, 512 thr / 8 waves, 1 tile/wave,
// (512,2) bounds = 128-VGPR cap, spill-free).
// mfma_f32_16x16x32_bf16: A[m=lane&15][k=(lane>>4)*8+j]; B[k][n=lane&15];
// C: col(n)=lane&15, row(m)=(lane>>4)*4+reg.
// ---------------------------------------------------------------------------
__global__ __launch_bounds__(512, 2) void score_kernel(
        const float* __restrict__ ent_emb, const unsigned short* __restrict__ w1tt,
        const float* __restrict__ phW, float* __restrict__ scores, int E) {
    __shared__ __align__(16) unsigned short wL[HDIM][WPAD];   // 69.6 KB
    __shared__ float phB[NB][HDIM];                           //  8 KB  [b][h]
    __shared__ float w2L[HDIM];                               //  1 KB

    const int tid = threadIdx.x;
    const int lane = tid & 63;
    const int wave = tid >> 6;          // 0..7
    const int lm = lane & 15;
    const int q = lane >> 4;
    const int base_e = blockIdx.x * 128 + wave * 16;

    const float* arow = ent_emb + (size_t)min(base_e + lm, E - 1) * D;
    bf16x8 aF[4];
#pragma unroll
    for (int kk = 0; kk < 4; ++kk) {
        const float4 u = *(const float4*)(arow + kk * 32 + q * 8);
        const float4 v = *(const float4*)(arow + kk * 32 + q * 8 + 4);
        aF[kk] = pack_bf8(u, v);
    }

#pragma unroll
    for (int i = 0; i < 8; ++i) {
        const int c = i * 512 + tid;           // chunk of 8 ushorts
        const int row = c >> 4;                // 16 chunks per 128-ushort row
        const int col = (c & 15) << 3;
        *(uint4*)(&wL[row][col]) = *(const uint4*)(w1tt + row * D + col);
    }
    if (tid < HDIM) {
        const float4 p0 = *(const float4*)(phW + tid * PHW);
        const float4 p1 = *(const float4*)(phW + tid * PHW + 4);
        phB[0][tid] = p0.x; phB[1][tid] = p0.y; phB[2][tid] = p0.z; phB[3][tid] = p0.w;
        phB[4][tid] = p1.x; phB[5][tid] = p1.y; phB[6][tid] = p1.z; phB[7][tid] = p1.w;
        w2L[tid] = phW[tid * PHW + 8];
    }
    __syncthreads();   // the ONLY barrier

    float sp[NB * 4];
#pragma unroll
    for (int i = 0; i < NB * 4; ++i) sp[i] = 0.f;

#pragma unroll
    for (int t = 0; t < 16; ++t) {
        const int h = t * 16 + lm;             // lane's B-row & C-col
        bf16x8 bF[4];
#pragma unroll
        for (int kk = 0; kk < 4; ++kk)
            bF[kk] = *(const bf16x8*)(&wL[h][kk * 32 + q * 8]);   // 2-way banks: free

        float phv[8];
#pragma unroll
        for (int b = 0; b < NB; ++b) phv[b] = phB[b][h];   // 16 banks + broadcast
        const float w2v = w2L[h];

        f32x4 acc = (f32x4){0.f, 0.f, 0.f, 0.f};
#pragma unroll
        for (int kk = 0; kk < 4; ++kk)
            acc = __builtin_amdgcn_mfma_f32_16x16x32_bf16(aF[kk], bF[kk], acc, 0, 0, 0);

#pragma unroll
        for (int b = 0; b < NB; ++b)
#pragma unroll
            for (int r = 0; r < 4; ++r)
                sp[b * 4 + r] += fmaxf(phv[b] + acc[r], 0.f) * w2v;
    }

#pragma unroll
    for (int m = 1; m <= 8; m <<= 1) {
#pragma unroll
        for (int i = 0; i < NB * 4; ++i)
            sp[i] += __shfl_xor(sp[i], m, 64);
    }
    if (lm == 0) {
#pragma unroll
        for (int r = 0; r < 4; ++r) {
            const int e = base_e + q * 4 + r;
            if (e < E) {
#pragma unroll
                for (int b = 0; b < NB; ++b)
                    scores[(size_t)b * E + e] = sp[b * 4 + r];
            }
        }
    }
}

// ---------------------------------------------------------------------------
// K3: shard top-16 + exact fp32 rescore. R18: 256 blocks = 8 rows x 32 shards
// (1 block/CU; halves per-block scan latency vs R16's 128 blocks). No
// device-scope fences/atomics (R8 lesson).
// ---------------------------------------------------------------------------
__global__ __launch_bounds__(256) void topk_rescore_kernel(
        const float* __restrict__ scores, int E,
        const float* __restrict__ ent_emb, const float* __restrict__ W1,
        const float* __restrict__ phW, const float* __restrict__ b2,
        unsigned long long* __restrict__ cand_exact) {
    const int b = blockIdx.x >> 5;
    const int s = blockIdx.x & 31;
    const int tid = threadIdx.x;
    const int lane = tid & 63;
    const int wave = tid >> 6;

    __shared__ unsigned long long cl[4 * CPS];
    __shared__ unsigned long long candk[CPS];
    __shared__ int eIdxs[CPS];
    __shared__ float entR[CPS][D];                 // 8 KB
    __shared__ float red[4][CPS];

    {
        const int shard = (E + NSHARD - 1) / NSHARD;
        const int start = s * shard;
        const int end = min(E, start + shard);
        const float* row = scores + (size_t)b * E;

        unsigned long long keys[CPS];
#pragma unroll
        for (int i = 0; i < CPS; ++i) keys[i] = 0ull;

        for (int e = start + tid; e < end; e += 256) {
            unsigned long long key = sk_encode(row[e], e);
            if (key > keys[CPS - 1]) {
#pragma unroll
                for (int j = 0; j < CPS; ++j) {
                    const bool gt = key > keys[j];
                    const unsigned long long mx = gt ? key : keys[j];
                    key = gt ? keys[j] : key;
                    keys[j] = mx;
                }
            }
        }
        for (int r = 0; r < CPS; ++r) {
            const unsigned long long m = wave_max64(keys[0]);
            if (keys[0] == m) {
#pragma unroll
                for (int j = 0; j < CPS - 1; ++j) keys[j] = keys[j + 1];
                keys[CPS - 1] = 0ull;
            }
            if (lane == 0) cl[wave * CPS + r] = m;
        }
        __syncthreads();
        if (wave == 0) {
            unsigned long long v = cl[lane];       // 64 candidates
            for (int r = 0; r < CPS; ++r) {
                const unsigned long long m = wave_max64(v);
                if (v == m) v = 0ull;
                if (lane == 0) candk[r] = m;
            }
        }
        __syncthreads();
    }

    if (tid < CPS) eIdxs[tid] = sk_idx(candk[tid]);
    __syncthreads();
    for (int t = tid; t < CPS * (D / 4); t += 256) {
        const int row = t >> 5, c4 = (t & 31) * 4;
        *(float4*)(&entR[row][c4]) =
            *(const float4*)(ent_emb + (size_t)eIdxs[row] * D + c4);
    }
    __syncthreads();

    const float* w1t = W1 + 2 * D * HDIM;          // thread owns h = tid
    float acc[CPS];
#pragma unroll
    for (int c = 0; c < CPS; ++c) acc[c] = 0.f;
    for (int d0 = 0; d0 < D; d0 += 4) {
        float w[4];
#pragma unroll
        for (int j = 0; j < 4; ++j) w[j] = w1t[(d0 + j) * HDIM + tid];  // coalesced
#pragma unroll
        for (int c = 0; c < CPS; ++c) {
            const float4 f = *(const float4*)(&entR[c][d0]);            // broadcast
            acc[c] += f.x * w[0] + f.y * w[1] + f.z * w[2] + f.w * w[3];
        }
    }
    const float phv = phW[tid * PHW + b];
    const float w2v = phW[tid * PHW + 8];
    float sc[CPS];
#pragma unroll
    for (int c = 0; c < CPS; ++c) sc[c] = fmaxf(acc[c] + phv, 0.f) * w2v;

#pragma unroll
    for (int m = 1; m <= 32; m <<= 1)
#pragma unroll
        for (int c = 0; c < CPS; ++c) sc[c] += __shfl_xor(sc[c], m, 64);
    if (lane == 0)
#pragma unroll
        for (int c = 0; c < CPS; ++c) red[wave][c] = sc[c];
    __syncthreads();
    if (tid < CPS) {
        const float v = red[0][tid] + red[1][tid] + red[2][tid] + red[3][tid] + b2[0];
        cand_exact[(size_t)(b * NSHARD + s) * CPS + tid] = sk_encode(v, eIdxs[tid]);
    }
}

// ---------------------------------------------------------------------------
// K4: final top-k per row from 512 exactly-scored keys. 1 block, wave = row.
// (R8-proven sort-8 merge path.)
// ---------------------------------------------------------------------------
__global__ __launch_bounds__(256) void final_kernel(
        const unsigned long long* __restrict__ cand_exact, int k,
        float* __restrict__ out) {
    const int lane = threadIdx.x & 63;
    const int wave = threadIdx.x >> 6;
    for (int b = wave; b < NB; b += 4) {
        unsigned long long lk[8];
#pragma unroll
        for (int j = 0; j < 8; ++j)
            lk[j] = cand_exact[(size_t)b * NCAND + j * 64 + lane];   // coalesced
        // sort descending (static-index bubble)
#pragma unroll
        for (int i = 0; i < 8; ++i)
#pragma unroll
            for (int j = 0; j < 7; ++j)
                if (lk[j] < lk[j + 1]) {
                    const unsigned long long t = lk[j];
                    lk[j] = lk[j + 1];
                    lk[j + 1] = t;
                }
        for (int r = 0; r < k; ++r) {
            const unsigned long long m = wave_max64(lk[0]);
            if (lk[0] == m) {                      // unique keys -> one owner
#pragma unroll
                for (int j = 0; j < 7; ++j) lk[j] = lk[j + 1];
                lk[7] = 0ull;
            }
            if (lane == 0) {
                out[b * k + r] = (float)sk_idx(m);            // indices
                out[NB * k + b * k + r] = sk_val(m);          // scores
            }
        }
    }
}

// ---------------------------------------------------------------------------
extern "C" void kernel_launch(void* const* d_in, const int* in_sizes, int n_in,
                              void* d_out, int out_size, void* d_ws, size_t ws_size,
                              hipStream_t stream) {
    const int*   head     = (const int*)d_in[0];
    const int*   relation = (const int*)d_in[1];
    const float* ent_emb  = (const float*)d_in[3];
    const float* rel_emb  = (const float*)d_in[4];
    const float* W1       = (const float*)d_in[5];
    const float* b1       = (const float*)d_in[6];
    const float* W2       = (const float*)d_in[7];
    const float* b2       = (const float*)d_in[8];

    const int B = in_sizes[0];          // 8
    const int E = in_sizes[3] / D;      // 50000
    int k = out_size / (2 * B);         // 10
    if (k > CPS) k = CPS;

    char* ws = (char*)d_ws;
    unsigned long long* cand_exact = (unsigned long long*)ws;       //  32 KB
    float*          phW       = (float*)(ws + 32768);               //  16 KB
    unsigned short* w1tt      = (unsigned short*)(ws + 49152);      //  64 KB
    float*          scores    = (float*)(ws + 114688);              // 1.6 MB
    float*          out       = (float*)d_out;

    prep_kernel<<<NB + 32, HDIM, 0, stream>>>(head, relation, ent_emb, rel_emb,
                                              W1, b1, W2, phW, w1tt);
    const int nblk = (E + 127) / 128;
    score_kernel<<<nblk, 512, 0, stream>>>(ent_emb, w1tt, phW, scores, E);
    topk_rescore_kernel<<<NB * NSHARD, 256, 0, stream>>>(
        scores, E, ent_emb, W1, phW, b2, cand_exact);
    final_kernel<<<1, 256, 0, stream>>>(cand_exact, k, out);
}